// Round 3
// baseline (308.155 us; speedup 1.0000x reference)
//
#include <hip/hip_runtime.h>
#include <hip/hip_bf16.h>

#define B_ 4
#define G_ 4096
#define F_ 256
#define U_ 128

typedef __bf16 v8bf __attribute__((ext_vector_type(8)));
typedef __bf16 v4bf __attribute__((ext_vector_type(4)));
typedef float f32x4 __attribute__((ext_vector_type(4)));

__device__ __forceinline__ unsigned short f2bf(float x) {
    union { float f; unsigned u; } v; v.f = x;
    unsigned r = v.u + 0x7FFFu + ((v.u >> 16) & 1u);
    return (unsigned short)(r >> 16);
}

typedef const __attribute__((address_space(1))) unsigned int* gas_t;
typedef __attribute__((address_space(3))) unsigned int* las_t;

__device__ __forceinline__ void gld16(const void* g, const void* l) {
    __builtin_amdgcn_global_load_lds((gas_t)(unsigned long long)g,
                                     (las_t)(unsigned)(unsigned long long)l, 16, 0, 0);
}

// Fragment-major layout convention ("A/B-frag"): for a [rows][k] bf16 matrix,
// chunk (r4 = row>>4, k5 = k>>5) holds 64 lanes x 16B; lane = ((k>>3)&3)*16 + (row&15),
// bytes j = k&7. One wave A- or B-fragment load = one coalesced 1KB read at lane*16.
// C-fragment layout for Ct: chunk (g>>4, h>>4), lane = ((g>>2)&3)*16 + (h&15), elem r = g&3.

// ---------------- prep: transpose w,w2 [256][128]f32 -> wT [128][256]bf16 ----------------
__global__ __launch_bounds__(256) void k_transpose_w(
    const float* __restrict__ w, const float* __restrict__ w2,
    unsigned short* __restrict__ wT, unsigned short* __restrict__ w2T)
{
    const float* src = blockIdx.x ? w2 : w;
    unsigned short* dst = blockIdx.x ? w2T : wT;
    int u = threadIdx.x & 127, kh = (threadIdx.x >> 7) * 128;
    for (int k = 0; k < 128; ++k)
        dst[(size_t)u * F_ + kh + k] = f2bf(src[(size_t)(kh + k) * U_ + u]);
}

// ---------------- prep: ai,aj [128][4096]f32 -> Ai/Aj fragment-major bf16 (1 MiB each) ---
__global__ __launch_bounds__(256) void k_transpose_aiaj(
    const float* __restrict__ ai, const float* __restrict__ aj,
    unsigned short* __restrict__ Ai, unsigned short* __restrict__ Aj)
{
    __shared__ unsigned short s_t[64 * 128];
    int blk = blockIdx.x;
    const float* src = (blk < 64) ? ai : aj;
    unsigned short* dst = (blk < 64) ? Ai : Aj;
    int gtile = (blk & 63) * 64;
    int tid = threadIdx.x;
    int gl = tid & 63, ub = tid >> 6;
    #pragma unroll
    for (int i = 0; i < 32; ++i) {
        int u = ub * 32 + i;
        float v = src[(size_t)u * G_ + gtile + gl];
        int ad = ((gl << 8) + (u << 1)) ^ ((gl & 7) << 4);
        *(unsigned short*)((char*)s_t + ad) = f2bf(v);
    }
    __syncthreads();
    // emit fragment-major: 16 chunks (g4l 0..3 x k5 0..3), 16 threads/chunk, 4 lanes each
    int c = tid >> 4, sub = tid & 15;
    int g4l = c >> 2, k5 = c & 3;
    #pragma unroll
    for (int q = 0; q < 4; ++q) {
        int l = sub * 4 + q;
        int g = g4l * 16 + (l & 15);
        int u = k5 * 32 + (l >> 4) * 8;
        uint4 v = *(const uint4*)((const char*)s_t + (g << 8) + ((u << 1) ^ ((g & 7) << 4)));
        *(uint4*)(dst + (((size_t)((gtile >> 4) + g4l) * 4 + k5) * 64 + l) * 8) = v;
    }
}

// ---------------- prep: Ct = C-fragment-major bf16(b_a - 1e9*(1-adj)), 32 MiB ------------
__global__ __launch_bounds__(256) void k_bias(
    const float* __restrict__ adj, const float* __restrict__ b_a,
    unsigned short* __restrict__ Ct)
{
    __shared__ unsigned short s_t[64 * 64];  // [h][g] bf16, swizzled
    int g0 = blockIdx.x * 64, h0 = blockIdx.y * 64;
    int tid = threadIdx.x;
    int hl = tid & 63, gb = tid >> 6;
    #pragma unroll
    for (int i = 0; i < 16; ++i) {
        int gl = gb * 16 + i;
        size_t gi = (size_t)(g0 + gl) * G_ + h0 + hl;
        float v = fmaf(adj[gi], 1e9f, -1e9f) + b_a[gi];
        int ad = ((hl << 7) + (gl << 1)) ^ ((hl & 7) << 4);
        *(unsigned short*)((char*)s_t + ad) = f2bf(v);
    }
    __syncthreads();
    // emit C-fragment chunks: 16 chunks (g4l x h4l), 16 threads/chunk, 4 lanes x 8B
    int c = tid >> 4, sub = tid & 15;
    int gg4 = (g0 >> 4) + (c >> 2);
    int hh4 = (h0 >> 4) + (c & 3);
    #pragma unroll
    for (int q = 0; q < 4; ++q) {
        int l = sub * 4 + q;
        int h = (c & 3) * 16 + (l & 15);
        int gcol = (c >> 2) * 16 + ((l >> 4) << 2);
        uint2 v = *(const uint2*)((const char*)s_t + (h << 7) + ((gcol << 1) ^ ((h & 7) << 4)));
        *(uint2*)(Ct + (((size_t)gg4 << 8) + hh4) * 256 + l * 4) = v;
    }
}

// ---------------- f = bf16(x@w) -> Ff/FfT fragment-major, g2 = f32(x@w_2) -> d_out -------
__global__ __launch_bounds__(256, 2) void k_gemm_f(
    const float* __restrict__ x,
    const unsigned short* __restrict__ wT, const unsigned short* __restrict__ w2T,
    unsigned short* __restrict__ Ff, unsigned short* __restrict__ FfT,
    float* __restrict__ g2_out)
{
    __shared__ unsigned short s_xa[128 * 128];
    __shared__ unsigned short s_w[128 * 128];
    __shared__ unsigned short s_w2[128 * 128];
    const int tid = threadIdx.x;
    const int lane = tid & 63, w = tid >> 6;
    const int l15 = lane & 15, l4 = lane >> 4;
    const int wm = w >> 1, wn = w & 1;
    const int mrow0 = blockIdx.x * 128;

    f32x4 zz = {0.f, 0.f, 0.f, 0.f};
    f32x4 accf[4][4], accg[4][4];
    #pragma unroll
    for (int i = 0; i < 4; ++i)
        #pragma unroll
        for (int j = 0; j < 4; ++j) { accf[i][j] = zz; accg[i][j] = zz; }

    for (int kc = 0; kc < 2; ++kc) {
        if (kc) __syncthreads();
        {   // stage x tile (f32 -> bf16, swizzled)
            int m = tid >> 1, half = tid & 1;
            const float* src = x + (size_t)(mrow0 + m) * F_ + kc * 128 + half * 64;
            unsigned tmp32[32];
            #pragma unroll
            for (int i = 0; i < 16; ++i) {
                float4 v = *(const float4*)(src + i * 4);
                tmp32[i * 2 + 0] = (unsigned)f2bf(v.x) | ((unsigned)f2bf(v.y) << 16);
                tmp32[i * 2 + 1] = (unsigned)f2bf(v.z) | ((unsigned)f2bf(v.w) << 16);
            }
            #pragma unroll
            for (int gi2 = 0; gi2 < 8; ++gi2) {
                int ad = (m << 8) + ((half * 128 + gi2 * 16) ^ ((m & 7) << 4));
                *(uint4*)((char*)s_xa + ad) = *(const uint4*)(tmp32 + gi2 * 4);
            }
        }
        #pragma unroll
        for (int i = 0; i < 8; ++i) {     // stage wT / w2T chunks
            int c = w * 8 + i;
            int row = c * 4 + l4;
            int Wp = (l15 << 4) ^ ((row & 7) << 4);
            gld16((const char*)wT  + (size_t)row * 512 + kc * 256 + Wp, (const char*)s_w  + c * 1024);
            gld16((const char*)w2T + (size_t)row * 512 + kc * 256 + Wp, (const char*)s_w2 + c * 1024);
        }
        __syncthreads();
        #pragma unroll
        for (int ks = 0; ks < 4; ++ks) {
            int kb = 64 * ks + 16 * l4;
            v8bf a[4], b1[4], b2[4];
            #pragma unroll
            for (int mf = 0; mf < 4; ++mf) {
                int m = l15 + 16 * mf + 64 * wm;
                int ad = (m << 8) + (kb ^ ((m & 7) << 4));
                a[mf] = *(const v8bf*)((const char*)s_xa + ad);
            }
            #pragma unroll
            for (int nf = 0; nf < 4; ++nf) {
                int u = l15 + 16 * nf + 64 * wn;
                int ad = (u << 8) + (kb ^ ((u & 7) << 4));
                b1[nf] = *(const v8bf*)((const char*)s_w + ad);
                b2[nf] = *(const v8bf*)((const char*)s_w2 + ad);
            }
            #pragma unroll
            for (int mf = 0; mf < 4; ++mf)
                #pragma unroll
                for (int nf = 0; nf < 4; ++nf) {
                    accf[mf][nf] = __builtin_amdgcn_mfma_f32_16x16x32_bf16(a[mf], b1[nf], accf[mf][nf], 0, 0, 0);
                    accg[mf][nf] = __builtin_amdgcn_mfma_f32_16x16x32_bf16(a[mf], b2[nf], accg[mf][nf], 0, 0, 0);
                }
        }
    }
    const int b = mrow0 >> 12, gb = mrow0 & 4095;
    // g2 (f32) direct to d_out
    #pragma unroll
    for (int mf = 0; mf < 4; ++mf)
        #pragma unroll
        for (int nf = 0; nf < 4; ++nf)
            #pragma unroll
            for (int r = 0; r < 4; ++r) {
                int m = 4 * l4 + r + 16 * mf + 64 * wm;
                int u = l15 + 16 * nf + 64 * wn;
                g2_out[(size_t)(mrow0 + m) * U_ + u] = accg[mf][nf][r];
            }
    // bounce f tile (bf16) into s_xa
    __syncthreads();
    #pragma unroll
    for (int mf = 0; mf < 4; ++mf)
        #pragma unroll
        for (int nf = 0; nf < 4; ++nf)
            #pragma unroll
            for (int r = 0; r < 4; ++r) {
                int m = 4 * l4 + r + 16 * mf + 64 * wm;
                int u = l15 + 16 * nf + 64 * wn;
                int ad = (m << 8) + ((u << 1) ^ ((m & 7) << 4));
                *(unsigned short*)((char*)s_xa + ad) = f2bf(accf[mf][nf][r]);
            }
    __syncthreads();
    // emit Ff: 32 chunks (g4l 0..7 x k5 0..3), 8 threads/chunk, 8 lanes each
    {
        unsigned short* Ffb = Ff + (size_t)b * (G_ * U_);
        int c = tid >> 3, sub = tid & 7;
        int g4l = c >> 2, k5 = c & 3;
        #pragma unroll
        for (int q = 0; q < 8; ++q) {
            int l = sub * 8 + q;
            int m = g4l * 16 + (l & 15);
            int k = k5 * 32 + (l >> 4) * 8;
            uint4 v = *(const uint4*)((const char*)s_xa + (m << 8) + ((k << 1) ^ ((m & 7) << 4)));
            *(uint4*)(Ffb + (((size_t)((gb >> 4) + g4l) * 4 + k5) * 64 + l) * 8) = v;
        }
    }
    // emit FfT: 32 chunks (u4 0..7 x g5l 0..3), gather-transpose from s_xa
    {
        unsigned short* FfTb = FfT + (size_t)b * (G_ * U_);
        int c = tid >> 3, sub = tid & 7;
        int u4 = c >> 2, g5l = c & 3;
        #pragma unroll
        for (int q = 0; q < 8; ++q) {
            int l = sub * 8 + q;
            int u = u4 * 16 + (l & 15);
            int g0l = g5l * 32 + (l >> 4) * 8;
            union { unsigned short s[8]; uint4 v; } pk;
            #pragma unroll
            for (int j = 0; j < 8; ++j) {
                int m = g0l + j;
                pk.s[j] = *(const unsigned short*)((const char*)s_xa + (m << 8) + ((u << 1) ^ ((m & 7) << 4)));
            }
            *(uint4*)(FfTb + (((size_t)u4 * 128 + (gb >> 5) + g5l) * 64 + l) * 8) = pk.v;
        }
    }
}

// ---------------- main fused: attn -> sigmoid gate (write) -> agg partial ----------------
__global__ __launch_bounds__(512, 4) void k_main(
    const unsigned short* __restrict__ Ct,
    const unsigned short* __restrict__ Ff,
    const unsigned short* __restrict__ FfT,
    const unsigned short* __restrict__ Ai,
    const unsigned short* __restrict__ Aj,
    float* __restrict__ gate_out,
    float* __restrict__ part)
{
    __shared__ unsigned short s_gT[128 * 128];   // 32 KB, gate^T bf16, XOR-swizzled
    const int tid = threadIdx.x;
    const int lane = tid & 63, w = tid >> 6;
    const int l15 = lane & 15, l4 = lane >> 4;
    const int htile = blockIdx.x * 128;
    const int split = blockIdx.y;                // 0..3
    const int b = blockIdx.z;
    const int wg = w >> 2, wh = w & 3;           // attn: g = l15+16mf+64wg, h = l15+16nf+32wh
    const int awm = w & 1, awn = w >> 1;         // agg:  h = 16mf+64awm,   u = l15+16nf+32awn

    const unsigned short* Ff_b  = Ff  + (size_t)b * (G_ * U_);
    const unsigned short* FfT_b = FfT + (size_t)b * (G_ * U_);
    float* gate_b = gate_out + ((size_t)b << 24);
    const int h4b = htile >> 4;

    f32x4 zz = {0.f, 0.f, 0.f, 0.f};
    f32x4 agga[4][2];
    #pragma unroll
    for (int i = 0; i < 4; ++i)
        #pragma unroll
        for (int j = 0; j < 2; ++j) agga[i][j] = zz;

    for (int it = 0; it < 8; ++it) {
        const int gtile = split * 1024 + it * 128;
        const int g4b = gtile >> 4;

        // ---- attn: acc[g'][h'] = f@ai + ajT@f' (fragments direct from global) ----
        f32x4 acc[4][2];
        #pragma unroll
        for (int mf = 0; mf < 4; ++mf)
            #pragma unroll
            for (int nf = 0; nf < 2; ++nf) acc[mf][nf] = zz;
        #pragma unroll
        for (int ks = 0; ks < 4; ++ks) {
            v8bf a1[4], a2[4], bih[2], bfh[2];
            #pragma unroll
            for (int mf = 0; mf < 4; ++mf) {
                int off = (((g4b + mf + 4 * wg) * 4 + ks) * 64 + lane) * 8;
                a1[mf] = *(const v8bf*)(Ff_b + off);
                a2[mf] = *(const v8bf*)(Aj + off);
            }
            #pragma unroll
            for (int nf = 0; nf < 2; ++nf) {
                int off = (((h4b + nf + 2 * wh) * 4 + ks) * 64 + lane) * 8;
                bih[nf] = *(const v8bf*)(Ai + off);
                bfh[nf] = *(const v8bf*)(Ff_b + off);
            }
            #pragma unroll
            for (int mf = 0; mf < 4; ++mf)
                #pragma unroll
                for (int nf = 0; nf < 2; ++nf) {
                    acc[mf][nf] = __builtin_amdgcn_mfma_f32_16x16x32_bf16(a1[mf], bih[nf], acc[mf][nf], 0, 0, 0);
                    acc[mf][nf] = __builtin_amdgcn_mfma_f32_16x16x32_bf16(a2[mf], bfh[nf], acc[mf][nf], 0, 0, 0);
                }
        }

        // ---- epilogue: bias + sigmoid -> gate (f32 global) + gate^T (bf16 LDS) ----
        #pragma unroll
        for (int mf = 0; mf < 4; ++mf)
            #pragma unroll
            for (int nf = 0; nf < 2; ++nf) {
                v4bf ctv = *(const v4bf*)(Ct + ((((size_t)(g4b + mf + 4 * wg)) << 8) + (h4b + nf + 2 * wh)) * 256 + lane * 4);
                int hp = l15 + 16 * nf + 32 * wh;
                float* grow = gate_b + (size_t)(gtile + 4 * l4 + 16 * mf + 64 * wg) * G_ + htile + hp;
                #pragma unroll
                for (int r = 0; r < 4; ++r) {
                    int gp = 4 * l4 + r + 16 * mf + 64 * wg;
                    float attn = acc[mf][nf][r] + (float)ctv[r];
                    float e = __expf(-attn);
                    float gv = __builtin_amdgcn_rcpf(1.0f + e);
                    grow[(size_t)r * G_] = gv;
                    *(unsigned short*)((char*)s_gT + (hp << 8) + ((gp << 1) ^ ((hp & 7) << 4))) = f2bf(gv);
                }
            }
        asm volatile("s_waitcnt lgkmcnt(0)" ::: "memory");
        __builtin_amdgcn_s_barrier();

        // ---- agg[h'][u] += gate^T @ f ----
        #pragma unroll
        for (int ks = 0; ks < 4; ++ks) {
            int kb = 64 * ks + 16 * l4;
            v8bf ag[4], bfv[2];
            #pragma unroll
            for (int nf = 0; nf < 2; ++nf) {
                int off = ((((size_t)(nf + 2 * awn)) * 128 + (gtile >> 5) + ks) * 64 + lane) * 8;
                bfv[nf] = *(const v8bf*)(FfT_b + off);
            }
            #pragma unroll
            for (int mf = 0; mf < 4; ++mf) {
                int hp = l15 + 16 * mf + 64 * awm;
                ag[mf] = *(const v8bf*)((const char*)s_gT + (hp << 8) + (kb ^ ((hp & 7) << 4)));
            }
            #pragma unroll
            for (int mf = 0; mf < 4; ++mf)
                #pragma unroll
                for (int nf = 0; nf < 2; ++nf)
                    agga[mf][nf] = __builtin_amdgcn_mfma_f32_16x16x32_bf16(ag[mf], bfv[nf], agga[mf][nf], 0, 0, 0);
        }
        asm volatile("s_waitcnt lgkmcnt(0)" ::: "memory");
        __builtin_amdgcn_s_barrier();
    }

    // write agg partial
    #pragma unroll
    for (int mf = 0; mf < 4; ++mf)
        #pragma unroll
        for (int nf = 0; nf < 2; ++nf) {
            int up = l15 + 16 * nf + 32 * awn;
            #pragma unroll
            for (int r = 0; r < 4; ++r) {
                int hp = 4 * l4 + r + 16 * mf + 64 * awm;
                part[(((size_t)b * 4 + split) << 19) + (size_t)(htile + hp) * U_ + up] = agga[mf][nf][r];
            }
        }
}

// ---------------- reduce: out = relu(part0..3 + g2) (g2 already in d_out) ----------------
__global__ __launch_bounds__(256) void k_reduce(const float4* __restrict__ part, float4* __restrict__ outio)
{
    int i = blockIdx.x * 256 + threadIdx.x;     // 0..524287 float4s
    int fb = i >> 17, r = i & 0x1FFFF;
    const float4* p = part + (((size_t)fb * 4) << 17) + r;
    float4 p0 = p[0];
    float4 p1 = p[(size_t)1 << 17];
    float4 p2 = p[(size_t)2 << 17];
    float4 p3 = p[(size_t)3 << 17];
    float4 g = outio[i];
    float4 o;
    o.x = fmaxf(p0.x + p1.x + p2.x + p3.x + g.x, 0.f);
    o.y = fmaxf(p0.y + p1.y + p2.y + p3.y + g.y, 0.f);
    o.z = fmaxf(p0.z + p1.z + p2.z + p3.z + g.z, 0.f);
    o.w = fmaxf(p0.w + p1.w + p2.w + p3.w + g.w, 0.f);
    outio[i] = o;
}

extern "C" void kernel_launch(void* const* d_in, const int* in_sizes, int n_in,
                              void* d_out, int out_size, void* d_ws, size_t ws_size,
                              hipStream_t stream)
{
    (void)in_sizes; (void)n_in; (void)out_size; (void)ws_size;
    const float* x   = (const float*)d_in[0];
    const float* adj = (const float*)d_in[1];
    const float* w   = (const float*)d_in[2];
    const float* ai  = (const float*)d_in[3];
    const float* aj  = (const float*)d_in[4];
    const float* w2  = (const float*)d_in[5];
    const float* ba  = (const float*)d_in[6];

    char* ws = (char*)d_ws;
    unsigned short* Ff  = (unsigned short*)(ws);                        // 4 MiB  [B] frag-major f
    unsigned short* FfT = (unsigned short*)(ws + ((size_t)4 << 20));    // 4 MiB  [B] frag-major fT
    unsigned short* Ai  = (unsigned short*)(ws + ((size_t)8 << 20));    // 1 MiB  frag-major aiT
    unsigned short* Aj  = (unsigned short*)(ws + ((size_t)9 << 20));    // 1 MiB  frag-major ajT
    unsigned short* wT  = (unsigned short*)(ws + ((size_t)10 << 20));   // 64 KiB
    unsigned short* w2T = (unsigned short*)(ws + ((size_t)10 << 20) + (1 << 17));
    float* part         = (float*)(ws + ((size_t)12 << 20));            // 32 MiB [B][4][G][U]
    unsigned short* Ct  = (unsigned short*)(ws + ((size_t)44 << 20));   // 32 MiB C-frag-major bias

    float* out  = (float*)d_out;                       // [B*G*U]
    float* gate = out + (size_t)B_ * G_ * U_;          // [B*G*G]

    k_transpose_w   <<<dim3(2),        dim3(256), 0, stream>>>(w, w2, wT, w2T);
    k_transpose_aiaj<<<dim3(128),      dim3(256), 0, stream>>>(ai, aj, Ai, Aj);
    k_bias          <<<dim3(64, 64),   dim3(256), 0, stream>>>(adj, ba, Ct);
    k_gemm_f        <<<dim3(128),      dim3(256), 0, stream>>>(x, wT, w2T, Ff, FfT, out);
    k_main          <<<dim3(32, 4, 4), dim3(512), 0, stream>>>(Ct, Ff, FfT, Ai, Aj, gate, part);
    k_reduce        <<<dim3(2048),     dim3(256), 0, stream>>>((const float4*)part, (float4*)out);
}

// Round 4
// 232.306 us; speedup vs baseline: 1.3265x; 1.3265x over previous
//
#include <hip/hip_runtime.h>
#include <hip/hip_bf16.h>

#define B_ 4
#define G_ 4096
#define F_ 256
#define U_ 128

typedef __bf16 v8bf __attribute__((ext_vector_type(8)));
typedef float f32x4 __attribute__((ext_vector_type(4)));

__device__ __forceinline__ unsigned short f2bf(float x) {
    union { float f; unsigned u; } v; v.f = x;
    unsigned r = v.u + 0x7FFFu + ((v.u >> 16) & 1u);
    return (unsigned short)(r >> 16);
}

typedef const __attribute__((address_space(1))) unsigned int* gas_t;
typedef __attribute__((address_space(3))) unsigned int* las_t;

// async global->LDS, 16B/lane; LDS dest = uniform base + lane*16; global src per-lane
__device__ __forceinline__ void gld16(const void* g, const void* l) {
    __builtin_amdgcn_global_load_lds((gas_t)(unsigned long long)g,
                                     (las_t)(unsigned)(unsigned long long)l, 16, 0, 0);
}

#define WAITV(n) asm volatile("s_waitcnt vmcnt(" #n ")" ::: "memory")
#define LGKM0    asm volatile("s_waitcnt lgkmcnt(0)" ::: "memory")
#define SBAR     __builtin_amdgcn_s_barrier()
#define SCHED0   __builtin_amdgcn_sched_barrier(0)

// Fragment-major convention: [row16-blk][k32-blk][lane][8 bf16];
// lane = ((k>>3)&3)*16 + (row&15). One frag load = 1KB coalesced / contiguous LDS.

// LDS arena byte offsets (k_main)
#define OFF_FG   0        // 2 x 16KB dbuf: Ff[g-tile] frags
#define OFF_AJ   32768    // 2 x 16KB dbuf: Aj[g-tile] frags
#define OFF_BA   65536    // 32KB: b_a f32 [g64][h128] (XOR-swizzled rows); prologue: Ai tile
#define OFF_BITS 98304    // 1KB: adjacency bits [g64][16B]
#define OFF_GT   99328    // 16KB: gate^T bf16 [h128][g64] XOR-swizzled
#define LDS_SZ   115712

// ---------------- prep: transpose w,w2 [256][128]f32 -> wT [128][256]bf16 ----------------
__global__ __launch_bounds__(256) void k_transpose_w(
    const float* __restrict__ w, const float* __restrict__ w2,
    unsigned short* __restrict__ wT, unsigned short* __restrict__ w2T)
{
    int bx = blockIdx.x;
    const float* src = (bx & 1) ? w2 : w;
    unsigned short* dst = (bx & 1) ? w2T : wT;
    int u = threadIdx.x & 127;
    int kseg = (threadIdx.x >> 7) + (bx >> 1) * 2;   // 0..15
    #pragma unroll
    for (int k = 0; k < 16; ++k) {
        int kk = kseg * 16 + k;
        dst[(size_t)u * F_ + kk] = f2bf(src[(size_t)kk * U_ + u]);
    }
}

// ---------------- prep: ai,aj [128][4096]f32 -> Ai/Aj fragment-major bf16 (1 MiB each) ---
__global__ __launch_bounds__(256) void k_transpose_aiaj(
    const float* __restrict__ ai, const float* __restrict__ aj,
    unsigned short* __restrict__ Ai, unsigned short* __restrict__ Aj)
{
    __shared__ unsigned short s_t[64 * 128];
    int blk = blockIdx.x;
    const float* src = (blk < 64) ? ai : aj;
    unsigned short* dst = (blk < 64) ? Ai : Aj;
    int gtile = (blk & 63) * 64;
    int tid = threadIdx.x;
    int gl = tid & 63, ub = tid >> 6;
    #pragma unroll
    for (int i = 0; i < 32; ++i) {
        int u = ub * 32 + i;
        float v = src[(size_t)u * G_ + gtile + gl];
        int ad = ((gl << 8) + (u << 1)) ^ ((gl & 7) << 4);
        *(unsigned short*)((char*)s_t + ad) = f2bf(v);
    }
    __syncthreads();
    // emit fragment-major: 16 chunks (r4 0..3 x k5 0..3), 16 threads/chunk, 4 lanes each
    int c = tid >> 4, sub = tid & 15;
    int g4l = c >> 2, k5 = c & 3;
    #pragma unroll
    for (int q = 0; q < 4; ++q) {
        int l = sub * 4 + q;
        int g = g4l * 16 + (l & 15);
        int u = k5 * 32 + (l >> 4) * 8;
        uint4 v = *(const uint4*)((const char*)s_t + (g << 8) + ((u << 1) ^ ((g & 7) << 4)));
        *(uint4*)(dst + (((size_t)((gtile >> 4) + g4l) * 4 + k5) * 64 + l) * 8) = v;
    }
}

// ---------------- prep: pack adjacency to bits[g][G/32] u32 (2 MiB) ----------------------
__global__ __launch_bounds__(256) void k_pack(
    const float* __restrict__ adj, unsigned* __restrict__ bits)
{
    int tid = threadIdx.x;
    int lane = tid & 63, w = tid >> 6;
    int wid = blockIdx.x * 4 + w;
    for (int i = wid; i < G_ * (G_ / 64); i += 4096) {
        int g = i >> 6, h0 = (i & 63) * 64;
        float v = adj[(size_t)g * G_ + h0 + lane];
        unsigned long long m = __ballot(v != 0.0f);
        if (lane < 2)
            bits[(size_t)g * (G_ / 32) + (h0 >> 5) + lane] = (unsigned)(m >> (lane * 32));
    }
}

// ---------------- f = bf16(x@w) -> Ff/FfT fragment-major, g2 = f32(x@w_2) -> d_out -------
__global__ __launch_bounds__(256, 2) void k_gemm_f(
    const float* __restrict__ x,
    const unsigned short* __restrict__ wT, const unsigned short* __restrict__ w2T,
    unsigned short* __restrict__ Ff, unsigned short* __restrict__ FfT,
    float* __restrict__ g2_out)
{
    __shared__ unsigned short s_xa[128 * 128];
    __shared__ unsigned short s_w[128 * 128];
    __shared__ unsigned short s_w2[128 * 128];
    const int tid = threadIdx.x;
    const int lane = tid & 63, w = tid >> 6;
    const int l15 = lane & 15, l4 = lane >> 4;
    const int wm = w >> 1, wn = w & 1;
    const int mrow0 = blockIdx.x * 128;

    f32x4 zz = {0.f, 0.f, 0.f, 0.f};
    f32x4 accf[4][4], accg[4][4];
    #pragma unroll
    for (int i = 0; i < 4; ++i)
        #pragma unroll
        for (int j = 0; j < 4; ++j) { accf[i][j] = zz; accg[i][j] = zz; }

    for (int kc = 0; kc < 2; ++kc) {
        if (kc) __syncthreads();
        {   // stage x tile (f32 -> bf16, swizzled)
            int m = tid >> 1, half = tid & 1;
            const float* src = x + (size_t)(mrow0 + m) * F_ + kc * 128 + half * 64;
            unsigned tmp32[32];
            #pragma unroll
            for (int i = 0; i < 16; ++i) {
                float4 v = *(const float4*)(src + i * 4);
                tmp32[i * 2 + 0] = (unsigned)f2bf(v.x) | ((unsigned)f2bf(v.y) << 16);
                tmp32[i * 2 + 1] = (unsigned)f2bf(v.z) | ((unsigned)f2bf(v.w) << 16);
            }
            #pragma unroll
            for (int gi2 = 0; gi2 < 8; ++gi2) {
                int ad = (m << 8) + ((half * 128 + gi2 * 16) ^ ((m & 7) << 4));
                *(uint4*)((char*)s_xa + ad) = *(const uint4*)(tmp32 + gi2 * 4);
            }
        }
        #pragma unroll
        for (int i = 0; i < 8; ++i) {     // stage wT / w2T chunks
            int c = w * 8 + i;
            int row = c * 4 + l4;
            int Wp = (l15 << 4) ^ ((row & 7) << 4);
            gld16((const char*)wT  + (size_t)row * 512 + kc * 256 + Wp, (const char*)s_w  + c * 1024);
            gld16((const char*)w2T + (size_t)row * 512 + kc * 256 + Wp, (const char*)s_w2 + c * 1024);
        }
        __syncthreads();
        #pragma unroll
        for (int ks = 0; ks < 4; ++ks) {
            int kb = 64 * ks + 16 * l4;
            v8bf a[4], b1[4], b2[4];
            #pragma unroll
            for (int mf = 0; mf < 4; ++mf) {
                int m = l15 + 16 * mf + 64 * wm;
                int ad = (m << 8) + (kb ^ ((m & 7) << 4));
                a[mf] = *(const v8bf*)((const char*)s_xa + ad);
            }
            #pragma unroll
            for (int nf = 0; nf < 4; ++nf) {
                int u = l15 + 16 * nf + 64 * wn;
                int ad = (u << 8) + (kb ^ ((u & 7) << 4));
                b1[nf] = *(const v8bf*)((const char*)s_w + ad);
                b2[nf] = *(const v8bf*)((const char*)s_w2 + ad);
            }
            #pragma unroll
            for (int mf = 0; mf < 4; ++mf)
                #pragma unroll
                for (int nf = 0; nf < 4; ++nf) {
                    accf[mf][nf] = __builtin_amdgcn_mfma_f32_16x16x32_bf16(a[mf], b1[nf], accf[mf][nf], 0, 0, 0);
                    accg[mf][nf] = __builtin_amdgcn_mfma_f32_16x16x32_bf16(a[mf], b2[nf], accg[mf][nf], 0, 0, 0);
                }
        }
    }
    const int b = mrow0 >> 12, gb = mrow0 & 4095;
    // g2 (f32) direct to d_out
    #pragma unroll
    for (int mf = 0; mf < 4; ++mf)
        #pragma unroll
        for (int nf = 0; nf < 4; ++nf)
            #pragma unroll
            for (int r = 0; r < 4; ++r) {
                int m = 4 * l4 + r + 16 * mf + 64 * wm;
                int u = l15 + 16 * nf + 64 * wn;
                g2_out[(size_t)(mrow0 + m) * U_ + u] = accg[mf][nf][r];
            }
    // bounce f tile (bf16) into s_xa
    __syncthreads();
    #pragma unroll
    for (int mf = 0; mf < 4; ++mf)
        #pragma unroll
        for (int nf = 0; nf < 4; ++nf)
            #pragma unroll
            for (int r = 0; r < 4; ++r) {
                int m = 4 * l4 + r + 16 * mf + 64 * wm;
                int u = l15 + 16 * nf + 64 * wn;
                int ad = (m << 8) + ((u << 1) ^ ((m & 7) << 4));
                *(unsigned short*)((char*)s_xa + ad) = f2bf(accf[mf][nf][r]);
            }
    __syncthreads();
    // emit Ff: 32 chunks (g4l 0..7 x k5 0..3)
    {
        unsigned short* Ffb = Ff + (size_t)b * (G_ * U_);
        int c = tid >> 3, sub = tid & 7;
        int g4l = c >> 2, k5 = c & 3;
        #pragma unroll
        for (int q = 0; q < 8; ++q) {
            int l = sub * 8 + q;
            int m = g4l * 16 + (l & 15);
            int k = k5 * 32 + (l >> 4) * 8;
            uint4 v = *(const uint4*)((const char*)s_xa + (m << 8) + ((k << 1) ^ ((m & 7) << 4)));
            *(uint4*)(Ffb + (((size_t)((gb >> 4) + g4l) * 4 + k5) * 64 + l) * 8) = v;
        }
    }
    // emit FfT: 32 chunks (u4 0..7 x g5l 0..3), gather-transpose from s_xa
    {
        unsigned short* FfTb = FfT + (size_t)b * (G_ * U_);
        int c = tid >> 3, sub = tid & 7;
        int u4 = c >> 2, g5l = c & 3;
        #pragma unroll
        for (int q = 0; q < 8; ++q) {
            int l = sub * 8 + q;
            int u = u4 * 16 + (l & 15);
            int g0l = g5l * 32 + (l >> 4) * 8;
            union { unsigned short s[8]; uint4 v; } pk;
            #pragma unroll
            for (int j = 0; j < 8; ++j) {
                int m = g0l + j;
                pk.s[j] = *(const unsigned short*)((const char*)s_xa + (m << 8) + ((u << 1) ^ ((m & 7) << 4)));
            }
            *(uint4*)(FfTb + (((size_t)u4 * 128 + (gb >> 5) + g5l) * 64 + l) * 8) = pk.v;
        }
    }
}

// ---------------- k_main helpers ----------------
__device__ __forceinline__ void stage_S(const unsigned short* Ff_b, const unsigned short* Aj,
                                        char* smem, int w, int lane, int gt, int bufb)
{
    #pragma unroll
    for (int i = 0; i < 2; ++i) {
        int c = 2 * w + i, g4l = c >> 2, ks = c & 3;
        size_t off = ((((size_t)(gt >> 4) + g4l) * 4 + ks) * 64 + lane) * 16;
        gld16((const char*)Ff_b + off, smem + OFF_FG + bufb * 16384 + c * 1024);
        gld16((const char*)Aj  + off, smem + OFF_AJ + bufb * 16384 + c * 1024);
    }
}

// ---------------- main fused: attn^T -> sigmoid gate -> agg partial ----------------------
__global__ __launch_bounds__(512, 2) void k_main(
    const unsigned short* __restrict__ Ff,   // [B] frag-major f
    const unsigned short* __restrict__ FfT,  // [B] frag-major fT [u4][g5][lane][8]
    const unsigned short* __restrict__ Ai,   // frag-major aiT
    const unsigned short* __restrict__ Aj,   // frag-major ajT
    const float* __restrict__ ba,            // [G][G] f32
    const unsigned* __restrict__ bits,       // [G][G/32]
    float* __restrict__ gate_out,            // [B][G][G] f32
    float* __restrict__ part)                // [B][2][G][U] f32
{
    __shared__ __align__(1024) char smem[LDS_SZ];
    const int tid = threadIdx.x;
    const int lane = tid & 63, w = tid >> 6;
    const int l15 = lane & 15, l4 = lane >> 4;
    const int wh = w >> 1, wg = w & 1, au = w & 1;
    const int fid = blockIdx.x;
    const int xcd = fid & 7, q = fid >> 3;
    const int b = xcd & 3, split = xcd >> 2;        // XCD-clustered: same htile across all b concurrently
    const int htile = q * 128;

    const unsigned short* Ff_b  = Ff  + (size_t)b * (G_ * U_);
    const unsigned short* FfT_b = FfT + (size_t)b * (G_ * U_);
    float* gate_b = gate_out + ((size_t)b << 24);

    // ---- prologue: stage Ai[htile], Ff[htile]; cache A-side fragments (h is M-dim) ----
    #pragma unroll
    for (int i = 0; i < 4; ++i) {
        int c = 4 * w + i, h4l = c >> 2, ks = c & 3;
        size_t off = ((((size_t)(htile >> 4) + h4l) * 4 + ks) * 64 + lane) * 16;
        gld16((const char*)Ai + off, smem + OFF_BA + c * 1024);
        gld16((const char*)Ff_b + off, smem + OFF_FG + c * 1024);
    }
    WAITV(0); SBAR;
    v8bf aih[2][4], fh[2][4];
    #pragma unroll
    for (int mf = 0; mf < 2; ++mf)
        #pragma unroll
        for (int ks = 0; ks < 4; ++ks) {
            int c = (2 * wh + mf) * 4 + ks;
            aih[mf][ks] = *(const v8bf*)(smem + OFF_BA + c * 1024 + lane * 16);
            fh[mf][ks]  = *(const v8bf*)(smem + OFF_FG + c * 1024 + lane * 16);
        }
    LGKM0; SBAR;
    stage_S(Ff_b, Aj, smem, w, lane, split * 2048, 0);
    WAITV(0);

    f32x4 zz = {0.f, 0.f, 0.f, 0.f};
    f32x4 agga[2][4];
    #pragma unroll
    for (int i = 0; i < 2; ++i)
        #pragma unroll
        for (int j = 0; j < 4; ++j) agga[i][j] = zz;

    for (int it = 0; it < 32; ++it) {
        const int gtile = split * 2048 + it * 64;

        // [top issues] Cba(it): 4 b_a chunks + 1 bits chunk
        #pragma unroll
        for (int i = 0; i < 4; ++i) {
            int c = 4 * w + i;
            int gl = 2 * c + (lane >> 5);
            int inrow = (lane & 31) * 16;
            gld16((const char*)ba + ((size_t)(gtile + gl) * G_ + htile) * 4 + (inrow ^ ((gl & 7) << 4)),
                  smem + OFF_BA + c * 1024);
        }
        gld16((const char*)bits + (size_t)(gtile + lane) * (G_ / 8) + (htile >> 3), smem + OFF_BITS);
        // S(it+1) double-buffered (tail read stays inside workspace: harmless)
        stage_S(Ff_b, Aj, smem, w, lane, gtile + 64, (it + 1) & 1);
        // V(it): FfT B-frags for agg, direct from global (L2-resident), a full phase early
        v8bf bfv[4][2];
        #pragma unroll
        for (int nf = 0; nf < 4; ++nf)
            #pragma unroll
            for (int ks = 0; ks < 2; ++ks)
                bfv[nf][ks] = *(const v8bf*)((const char*)FfT_b +
                    (((size_t)(4 * au + nf) * 128 + (gtile >> 5) + ks) * 64 + lane) * 16);

        // [B1] S(it) complete (issued last iter); counted: newer ops = 8+4+5+4+8 = 29
        WAITV(29); SBAR; SCHED0;

        // ---- attn^T: acc[h][g] = ai[:,h]·f[g] + f[h]·aj[:,g] ----
        f32x4 acc[2][2];
        #pragma unroll
        for (int i = 0; i < 2; ++i)
            #pragma unroll
            for (int j = 0; j < 2; ++j) acc[i][j] = zz;
        {
            const char* bfg = smem + OFF_FG + (it & 1) * 16384;
            const char* baj = smem + OFF_AJ + (it & 1) * 16384;
            #pragma unroll
            for (int ks = 0; ks < 4; ++ks) {
                v8bf fgv[2], ajv[2];
                #pragma unroll
                for (int nf = 0; nf < 2; ++nf) {
                    int c = (2 * wg + nf) * 4 + ks;
                    fgv[nf] = *(const v8bf*)(bfg + c * 1024 + lane * 16);
                    ajv[nf] = *(const v8bf*)(baj + c * 1024 + lane * 16);
                }
                #pragma unroll
                for (int mf = 0; mf < 2; ++mf)
                    #pragma unroll
                    for (int nf = 0; nf < 2; ++nf) {
                        acc[mf][nf] = __builtin_amdgcn_mfma_f32_16x16x32_bf16(aih[mf][ks], fgv[nf], acc[mf][nf], 0, 0, 0);
                        acc[mf][nf] = __builtin_amdgcn_mfma_f32_16x16x32_bf16(fh[mf][ks],  ajv[nf], acc[mf][nf], 0, 0, 0);
                    }
            }
        }

        // [B2] Cba(it) complete; counted: newer = S(it+1)4 + V(it)8 = 12 (also retires aged W(it-1))
        WAITV(12); SBAR; SCHED0;

        // ---- epilogue: bias + mask + sigmoid -> gate (f32, dwordx4) + gate^T (LDS bf16) ----
        #pragma unroll
        for (int nf = 0; nf < 2; ++nf) {
            int gl = 32 * wg + 16 * nf + l15;
            unsigned word = *(const unsigned*)(smem + OFF_BITS + gl * 16 + wh * 4);
            #pragma unroll
            for (int mf = 0; mf < 2; ++mf) {
                int h0 = 32 * wh + 16 * mf + 4 * l4;
                f32x4 bav = *(const f32x4*)(smem + OFF_BA + gl * 512 + ((h0 * 4) ^ ((gl & 7) << 4)));
                f32x4 gs;
                #pragma unroll
                for (int r = 0; r < 4; ++r) {
                    float attnv = acc[mf][nf][r] + bav[r];
                    float e = __expf(-attnv);
                    float gv = __builtin_amdgcn_rcpf(1.0f + e);
                    unsigned bit = (word >> (16 * mf + 4 * l4 + r)) & 1u;
                    gv = bit ? gv : 0.0f;
                    gs[r] = gv;
                    int hL = h0 + r;
                    *(unsigned short*)(smem + OFF_GT + hL * 128 + ((gl * 2) ^ ((hL & 7) << 4))) = f2bf(gv);
                }
                *(f32x4*)(gate_b + (size_t)(gtile + gl) * G_ + htile + h0) = gs;
            }
        }

        // [B3] gate^T visible; no vmcnt (stores sail on, V handled by compiler)
        LGKM0; SBAR; SCHED0;

        // ---- agg[h][u] += gate^T @ fT ----
        #pragma unroll
        for (int ks = 0; ks < 2; ++ks) {
            v8bf ag[2];
            #pragma unroll
            for (int amf = 0; amf < 2; ++amf) {
                int hL = 16 * (2 * wh + amf) + l15;
                ag[amf] = *(const v8bf*)(smem + OFF_GT + hL * 128 + (((32 * ks + 8 * l4) * 2) ^ ((hL & 7) << 4)));
            }
            #pragma unroll
            for (int amf = 0; amf < 2; ++amf)
                #pragma unroll
                for (int nf = 0; nf < 4; ++nf)
                    agga[amf][nf] = __builtin_amdgcn_mfma_f32_16x16x32_bf16(ag[amf], bfv[nf][ks], agga[amf][nf], 0, 0, 0);
        }
    }

    // write agg partial
    #pragma unroll
    for (int amf = 0; amf < 2; ++amf)
        #pragma unroll
        for (int nf = 0; nf < 4; ++nf) {
            int u = 64 * au + 16 * nf + l15;
            #pragma unroll
            for (int r = 0; r < 4; ++r) {
                int h = htile + 32 * wh + 16 * amf + 4 * l4 + r;
                part[(((size_t)b * 2 + split) << 19) + (size_t)h * U_ + u] = agga[amf][nf][r];
            }
        }
}

// ---------------- reduce: out = relu(part0 + part1 + g2) (g2 already in d_out) ----------
__global__ __launch_bounds__(256) void k_reduce(const float4* __restrict__ part, float4* __restrict__ outio)
{
    int i = blockIdx.x * 256 + threadIdx.x;     // 0..524287 float4s
    int fb = i >> 17, r = i & 0x1FFFF;
    const float4* p = part + ((size_t)fb << 18) + r;
    float4 p0 = p[0];
    float4 p1 = p[(size_t)1 << 17];
    float4 g = outio[i];
    float4 o;
    o.x = fmaxf(p0.x + p1.x + g.x, 0.f);
    o.y = fmaxf(p0.y + p1.y + g.y, 0.f);
    o.z = fmaxf(p0.z + p1.z + g.z, 0.f);
    o.w = fmaxf(p0.w + p1.w + g.w, 0.f);
    outio[i] = o;
}

extern "C" void kernel_launch(void* const* d_in, const int* in_sizes, int n_in,
                              void* d_out, int out_size, void* d_ws, size_t ws_size,
                              hipStream_t stream)
{
    (void)in_sizes; (void)n_in; (void)out_size; (void)ws_size;
    const float* x   = (const float*)d_in[0];
    const float* adj = (const float*)d_in[1];
    const float* w   = (const float*)d_in[2];
    const float* ai  = (const float*)d_in[3];
    const float* aj  = (const float*)d_in[4];
    const float* w2  = (const float*)d_in[5];
    const float* ba  = (const float*)d_in[6];

    char* ws = (char*)d_ws;
    unsigned short* Ff  = (unsigned short*)(ws);                        // 4 MiB
    unsigned short* FfT = (unsigned short*)(ws + ((size_t)4 << 20));    // 4 MiB
    unsigned short* Ai  = (unsigned short*)(ws + ((size_t)8 << 20));    // 1 MiB
    unsigned short* Aj  = (unsigned short*)(ws + ((size_t)9 << 20));    // 1 MiB
    unsigned short* wT  = (unsigned short*)(ws + ((size_t)10 << 20));   // 64 KiB
    unsigned short* w2T = (unsigned short*)(ws + ((size_t)10 << 20) + (1 << 17));
    unsigned* bitsb     = (unsigned*)(ws + ((size_t)11 << 20));         // 2 MiB
    float* part         = (float*)(ws + ((size_t)13 << 20));            // 16 MiB [B][2][G][U]

    float* out  = (float*)d_out;                       // [B*G*U]
    float* gate = out + (size_t)B_ * G_ * U_;          // [B*G*G]

    k_transpose_w   <<<dim3(16),   dim3(256), 0, stream>>>(w, w2, wT, w2T);
    k_transpose_aiaj<<<dim3(128),  dim3(256), 0, stream>>>(ai, aj, Ai, Aj);
    k_pack          <<<dim3(1024), dim3(256), 0, stream>>>(adj, bitsb);
    k_gemm_f        <<<dim3(128),  dim3(256), 0, stream>>>(x, wT, w2T, Ff, FfT, out);
    k_main          <<<dim3(256),  dim3(512), 0, stream>>>(Ff, FfT, Ai, Aj, ba, bitsb, gate, part);
    k_reduce        <<<dim3(2048), dim3(256), 0, stream>>>((const float4*)part, (float4*)out);
}

// Round 5
// 225.681 us; speedup vs baseline: 1.3654x; 1.0294x over previous
//
#include <hip/hip_runtime.h>
#include <hip/hip_bf16.h>

#define B_ 4
#define G_ 4096
#define F_ 256
#define U_ 128

typedef __bf16 v8bf __attribute__((ext_vector_type(8)));
typedef float f32x4 __attribute__((ext_vector_type(4)));

__device__ __forceinline__ unsigned short f2bf(float x) {
    union { float f; unsigned u; } v; v.f = x;
    unsigned r = v.u + 0x7FFFu + ((v.u >> 16) & 1u);
    return (unsigned short)(r >> 16);
}

typedef const __attribute__((address_space(1))) unsigned int* gas_t;
typedef __attribute__((address_space(3))) unsigned int* las_t;

// async global->LDS, 16B/lane; LDS dest = uniform base + lane*16; global src per-lane
__device__ __forceinline__ void gld16(const void* g, const void* l) {
    __builtin_amdgcn_global_load_lds((gas_t)(unsigned long long)g,
                                     (las_t)(unsigned)(unsigned long long)l, 16, 0, 0);
}

#define WAITV(n) asm volatile("s_waitcnt vmcnt(" #n ")" ::: "memory")
#define LGKM0    asm volatile("s_waitcnt lgkmcnt(0)" ::: "memory")
#define SBAR     __builtin_amdgcn_s_barrier()
#define SCHED0   __builtin_amdgcn_sched_barrier(0)

// Fragment-major convention: [row16-blk][k32-blk][lane][8 bf16];
// lane = ((k>>3)&3)*16 + (row&15). One frag load = 1KB coalesced / contiguous LDS.

// LDS arena byte offsets (k_main)
#define OFF_FG   0        // 2 x 16KB dbuf: Ff[g-tile] frags
#define OFF_AJ   32768    // 2 x 16KB dbuf: Aj[g-tile] frags
#define OFF_BA   65536    // 2 x 32KB dbuf: b_a f32 [g64][h128] XOR-swizzled (prologue: Ai tile)
#define OFF_BITS 131072   // 2 x 1KB dbuf: adjacency bits [g64][16B]
#define OFF_GT   133120   // 16KB: gate^T bf16 [h128][g64] XOR-swizzled
#define LDS_SZ   149504

// ---------------- prep: transpose w,w2 [256][128]f32 -> wT [128][256]bf16 ----------------
__global__ __launch_bounds__(256) void k_transpose_w(
    const float* __restrict__ w, const float* __restrict__ w2,
    unsigned short* __restrict__ wT, unsigned short* __restrict__ w2T)
{
    int bx = blockIdx.x;
    const float* src = (bx & 1) ? w2 : w;
    unsigned short* dst = (bx & 1) ? w2T : wT;
    int u = threadIdx.x & 127;
    int kseg = (threadIdx.x >> 7) + (bx >> 1) * 2;   // 0..15
    #pragma unroll
    for (int k = 0; k < 16; ++k) {
        int kk = kseg * 16 + k;
        dst[(size_t)u * F_ + kk] = f2bf(src[(size_t)kk * U_ + u]);
    }
}

// ---------------- prep: ai,aj [128][4096]f32 -> Ai/Aj fragment-major bf16 (1 MiB each) ---
__global__ __launch_bounds__(256) void k_transpose_aiaj(
    const float* __restrict__ ai, const float* __restrict__ aj,
    unsigned short* __restrict__ Ai, unsigned short* __restrict__ Aj)
{
    __shared__ unsigned short s_t[64 * 128];
    int blk = blockIdx.x;
    const float* src = (blk < 64) ? ai : aj;
    unsigned short* dst = (blk < 64) ? Ai : Aj;
    int gtile = (blk & 63) * 64;
    int tid = threadIdx.x;
    int gl = tid & 63, ub = tid >> 6;
    #pragma unroll
    for (int i = 0; i < 32; ++i) {
        int u = ub * 32 + i;
        float v = src[(size_t)u * G_ + gtile + gl];
        int ad = ((gl << 8) + (u << 1)) ^ ((gl & 7) << 4);
        *(unsigned short*)((char*)s_t + ad) = f2bf(v);
    }
    __syncthreads();
    // emit fragment-major: 16 chunks (r4 0..3 x k5 0..3), 16 threads/chunk, 4 lanes each
    int c = tid >> 4, sub = tid & 15;
    int g4l = c >> 2, k5 = c & 3;
    #pragma unroll
    for (int q = 0; q < 4; ++q) {
        int l = sub * 4 + q;
        int g = g4l * 16 + (l & 15);
        int u = k5 * 32 + (l >> 4) * 8;
        uint4 v = *(const uint4*)((const char*)s_t + (g << 8) + ((u << 1) ^ ((g & 7) << 4)));
        *(uint4*)(dst + (((size_t)((gtile >> 4) + g4l) * 4 + k5) * 64 + l) * 8) = v;
    }
}

// ---------------- prep: pack adjacency to bits[g][G/32] u32 (2 MiB) ----------------------
__global__ __launch_bounds__(256) void k_pack(
    const float* __restrict__ adj, unsigned* __restrict__ bits)
{
    int tid = threadIdx.x;
    int lane = tid & 63, w = tid >> 6;
    int wid = blockIdx.x * 4 + w;
    for (int i = wid; i < G_ * (G_ / 64); i += 4096) {
        int g = i >> 6, h0 = (i & 63) * 64;
        float v = adj[(size_t)g * G_ + h0 + lane];
        unsigned long long m = __ballot(v != 0.0f);
        if (lane < 2)
            bits[(size_t)g * (G_ / 32) + (h0 >> 5) + lane] = (unsigned)(m >> (lane * 32));
    }
}

// ---------------- f = bf16(x@w) -> Ff/FfT fragment-major, g2 = f32(x@w_2) -> d_out -------
__global__ __launch_bounds__(256, 2) void k_gemm_f(
    const float* __restrict__ x,
    const unsigned short* __restrict__ wT, const unsigned short* __restrict__ w2T,
    unsigned short* __restrict__ Ff, unsigned short* __restrict__ FfT,
    float* __restrict__ g2_out)
{
    __shared__ unsigned short s_xa[128 * 128];
    __shared__ unsigned short s_w[128 * 128];
    __shared__ unsigned short s_w2[128 * 128];
    const int tid = threadIdx.x;
    const int lane = tid & 63, w = tid >> 6;
    const int l15 = lane & 15, l4 = lane >> 4;
    const int wm = w >> 1, wn = w & 1;
    const int mrow0 = blockIdx.x * 128;

    f32x4 zz = {0.f, 0.f, 0.f, 0.f};
    f32x4 accf[4][4], accg[4][4];
    #pragma unroll
    for (int i = 0; i < 4; ++i)
        #pragma unroll
        for (int j = 0; j < 4; ++j) { accf[i][j] = zz; accg[i][j] = zz; }

    for (int kc = 0; kc < 2; ++kc) {
        if (kc) __syncthreads();
        {   // stage x tile (f32 -> bf16, swizzled)
            int m = tid >> 1, half = tid & 1;
            const float* src = x + (size_t)(mrow0 + m) * F_ + kc * 128 + half * 64;
            unsigned tmp32[32];
            #pragma unroll
            for (int i = 0; i < 16; ++i) {
                float4 v = *(const float4*)(src + i * 4);
                tmp32[i * 2 + 0] = (unsigned)f2bf(v.x) | ((unsigned)f2bf(v.y) << 16);
                tmp32[i * 2 + 1] = (unsigned)f2bf(v.z) | ((unsigned)f2bf(v.w) << 16);
            }
            #pragma unroll
            for (int gi2 = 0; gi2 < 8; ++gi2) {
                int ad = (m << 8) + ((half * 128 + gi2 * 16) ^ ((m & 7) << 4));
                *(uint4*)((char*)s_xa + ad) = *(const uint4*)(tmp32 + gi2 * 4);
            }
        }
        #pragma unroll
        for (int i = 0; i < 8; ++i) {     // stage wT / w2T chunks
            int c = w * 8 + i;
            int row = c * 4 + l4;
            int Wp = (l15 << 4) ^ ((row & 7) << 4);
            gld16((const char*)wT  + (size_t)row * 512 + kc * 256 + Wp, (const char*)s_w  + c * 1024);
            gld16((const char*)w2T + (size_t)row * 512 + kc * 256 + Wp, (const char*)s_w2 + c * 1024);
        }
        __syncthreads();
        #pragma unroll
        for (int ks = 0; ks < 4; ++ks) {
            int kb = 64 * ks + 16 * l4;
            v8bf a[4], b1[4], b2[4];
            #pragma unroll
            for (int mf = 0; mf < 4; ++mf) {
                int m = l15 + 16 * mf + 64 * wm;
                int ad = (m << 8) + (kb ^ ((m & 7) << 4));
                a[mf] = *(const v8bf*)((const char*)s_xa + ad);
            }
            #pragma unroll
            for (int nf = 0; nf < 4; ++nf) {
                int u = l15 + 16 * nf + 64 * wn;
                int ad = (u << 8) + (kb ^ ((u & 7) << 4));
                b1[nf] = *(const v8bf*)((const char*)s_w + ad);
                b2[nf] = *(const v8bf*)((const char*)s_w2 + ad);
            }
            #pragma unroll
            for (int mf = 0; mf < 4; ++mf)
                #pragma unroll
                for (int nf = 0; nf < 4; ++nf) {
                    accf[mf][nf] = __builtin_amdgcn_mfma_f32_16x16x32_bf16(a[mf], b1[nf], accf[mf][nf], 0, 0, 0);
                    accg[mf][nf] = __builtin_amdgcn_mfma_f32_16x16x32_bf16(a[mf], b2[nf], accg[mf][nf], 0, 0, 0);
                }
        }
    }
    const int b = mrow0 >> 12, gb = mrow0 & 4095;
    // g2 (f32) direct to d_out
    #pragma unroll
    for (int mf = 0; mf < 4; ++mf)
        #pragma unroll
        for (int nf = 0; nf < 4; ++nf)
            #pragma unroll
            for (int r = 0; r < 4; ++r) {
                int m = 4 * l4 + r + 16 * mf + 64 * wm;
                int u = l15 + 16 * nf + 64 * wn;
                g2_out[(size_t)(mrow0 + m) * U_ + u] = accg[mf][nf][r];
            }
    // bounce f tile (bf16) into s_xa
    __syncthreads();
    #pragma unroll
    for (int mf = 0; mf < 4; ++mf)
        #pragma unroll
        for (int nf = 0; nf < 4; ++nf)
            #pragma unroll
            for (int r = 0; r < 4; ++r) {
                int m = 4 * l4 + r + 16 * mf + 64 * wm;
                int u = l15 + 16 * nf + 64 * wn;
                int ad = (m << 8) + ((u << 1) ^ ((m & 7) << 4));
                *(unsigned short*)((char*)s_xa + ad) = f2bf(accf[mf][nf][r]);
            }
    __syncthreads();
    // emit Ff: 32 chunks (g4l 0..7 x k5 0..3)
    {
        unsigned short* Ffb = Ff + (size_t)b * (G_ * U_);
        int c = tid >> 3, sub = tid & 7;
        int g4l = c >> 2, k5 = c & 3;
        #pragma unroll
        for (int q = 0; q < 8; ++q) {
            int l = sub * 8 + q;
            int m = g4l * 16 + (l & 15);
            int k = k5 * 32 + (l >> 4) * 8;
            uint4 v = *(const uint4*)((const char*)s_xa + (m << 8) + ((k << 1) ^ ((m & 7) << 4)));
            *(uint4*)(Ffb + (((size_t)((gb >> 4) + g4l) * 4 + k5) * 64 + l) * 8) = v;
        }
    }
    // emit FfT: 32 chunks (u4 0..7 x g5l 0..3), gather-transpose from s_xa
    {
        unsigned short* FfTb = FfT + (size_t)b * (G_ * U_);
        int c = tid >> 3, sub = tid & 7;
        int u4 = c >> 2, g5l = c & 3;
        #pragma unroll
        for (int q = 0; q < 8; ++q) {
            int l = sub * 8 + q;
            int u = u4 * 16 + (l & 15);
            int g0l = g5l * 32 + (l >> 4) * 8;
            union { unsigned short s[8]; uint4 v; } pk;
            #pragma unroll
            for (int j = 0; j < 8; ++j) {
                int m = g0l + j;
                pk.s[j] = *(const unsigned short*)((const char*)s_xa + (m << 8) + ((u << 1) ^ ((m & 7) << 4)));
            }
            *(uint4*)(FfTb + (((size_t)u4 * 128 + (gb >> 5) + g5l) * 64 + l) * 8) = pk.v;
        }
    }
}

// ---------------- k_main helpers ----------------
__device__ __forceinline__ void stage_S(const unsigned short* Ff_b, const unsigned short* Aj,
                                        char* smem, int w, int lane, int gt, int bufb)
{
    #pragma unroll
    for (int i = 0; i < 2; ++i) {
        int c = 2 * w + i, g4l = c >> 2, ks = c & 3;
        size_t off = ((((size_t)(gt >> 4) + g4l) * 4 + ks) * 64 + lane) * 16;
        gld16((const char*)Ff_b + off, smem + OFF_FG + bufb * 16384 + c * 1024);
        gld16((const char*)Aj  + off, smem + OFF_AJ + bufb * 16384 + c * 1024);
    }
}

// Per-iter VMEM issue order (per thread), FIFO-counted:
//   [c] V 8  [a] bias 4 + bits 1  [b] S 4  ...B1... attn ...B2... [e] St 4 ...B3... agg
// B1 needs S(it)   (= [b] of it-1): newer = e(4)+c(8)+a(5)+b(4) = 21 -> WAITV(21)
// B2 needs bias(it) (= [a] of it-1): newer = b(4)+e(4)+c(8)+a(5)+b(4) = 25 -> WAITV(25)
// Neither wait forces stores to retire (stores are among the "newer" set).
__global__ __launch_bounds__(512, 2) void k_main(
    const unsigned short* __restrict__ Ff,   // [B] frag-major f
    const unsigned short* __restrict__ FfT,  // [B] frag-major fT [u4][g5][lane][8]
    const unsigned short* __restrict__ Ai,   // frag-major aiT
    const unsigned short* __restrict__ Aj,   // frag-major ajT
    const float* __restrict__ ba,            // [G][G] f32
    const unsigned* __restrict__ bits,       // [G][G/32]
    float* __restrict__ gate_out,            // [B][G][G] f32
    float* __restrict__ part)                // [B][2][G][U] f32
{
    __shared__ __align__(1024) char smem[LDS_SZ];
    const int tid = threadIdx.x;
    const int lane = tid & 63, w = tid >> 6;
    const int l15 = lane & 15, l4 = lane >> 4;
    const int wh = w >> 1, wg = w & 1, au = w & 1;
    // XCD-clustering: 4 batches of one (split,htile) tile share an XCD (same L2) under
    // both round-robin (bid&7) and 32-chunked blockIdx->XCD mappings.
    const int bid = blockIdx.x;
    const int xcd = bid & 7;
    const int rest = bid >> 3;               // 0..31
    const int b = rest & 3;
    const int tile = (rest >> 2) * 8 + xcd;  // 0..63
    const int split = tile & 1;
    const int htile = (tile >> 1) * 128;

    const unsigned short* Ff_b  = Ff  + (size_t)b * (G_ * U_);
    const unsigned short* FfT_b = FfT + (size_t)b * (G_ * U_);
    float* gate_b = gate_out + ((size_t)b << 24);

    // ---- prologue: stage Ai[htile], Ff[htile]; cache A-side fragments (h is M-dim) ----
    #pragma unroll
    for (int i = 0; i < 4; ++i) {
        int c = 4 * w + i, h4l = c >> 2, ks = c & 3;
        size_t off = ((((size_t)(htile >> 4) + h4l) * 4 + ks) * 64 + lane) * 16;
        gld16((const char*)Ai + off, smem + OFF_BA + c * 1024);
        gld16((const char*)Ff_b + off, smem + OFF_FG + c * 1024);
    }
    WAITV(0); SBAR;
    v8bf aih[2][4], fh[2][4];
    #pragma unroll
    for (int mf = 0; mf < 2; ++mf)
        #pragma unroll
        for (int ks = 0; ks < 4; ++ks) {
            int c = (2 * wh + mf) * 4 + ks;
            aih[mf][ks] = *(const v8bf*)(smem + OFF_BA + c * 1024 + lane * 16);
            fh[mf][ks]  = *(const v8bf*)(smem + OFF_FG + c * 1024 + lane * 16);
        }
    LGKM0; SBAR;
    // prime iter 0: bias+bits -> slot 0, S -> buf 0
    {
        const int g0 = split * 2048;
        #pragma unroll
        for (int i = 0; i < 4; ++i) {
            int c = 4 * w + i;
            int row = 2 * c + (lane >> 5);
            int inrow = (lane & 31) * 16;
            gld16((const char*)ba + ((size_t)(g0 + row) * G_ + htile) * 4 + (inrow ^ ((row & 7) << 4)),
                  smem + OFF_BA + c * 1024);
        }
        gld16((const char*)bits + (size_t)(g0 + lane) * (G_ / 8) + (htile >> 3), smem + OFF_BITS);
        stage_S(Ff_b, Aj, smem, w, lane, g0, 0);
    }
    WAITV(0); SBAR;

    f32x4 zz = {0.f, 0.f, 0.f, 0.f};
    f32x4 agga[2][4];
    #pragma unroll
    for (int i = 0; i < 2; ++i)
        #pragma unroll
        for (int j = 0; j < 4; ++j) agga[i][j] = zz;

    for (int it = 0; it < 32; ++it) {
        const int gtile = split * 2048 + it * 64;
        const int itn = (it < 31) ? it + 1 : 31;        // clamp: no OOB, same op count
        const int gnext = split * 2048 + itn * 64;
        const int sl = it & 1, sln = (it + 1) & 1;

        // [c] V(it): FfT B-frags for agg, direct from global (L2-resident)
        v8bf bfv[4][2];
        #pragma unroll
        for (int nf = 0; nf < 4; ++nf)
            #pragma unroll
            for (int ks = 0; ks < 2; ++ks)
                bfv[nf][ks] = *(const v8bf*)((const char*)FfT_b +
                    (((size_t)(4 * au + nf) * 128 + (gtile >> 5) + ks) * 64 + lane) * 16);
        // [a] bias(it+1) + bits(it+1) -> slot sln (one full iteration of latency cover)
        #pragma unroll
        for (int i = 0; i < 4; ++i) {
            int c = 4 * w + i;
            int row = 2 * c + (lane >> 5);
            int inrow = (lane & 31) * 16;
            gld16((const char*)ba + ((size_t)(gnext + row) * G_ + htile) * 4 + (inrow ^ ((row & 7) << 4)),
                  smem + OFF_BA + sln * 32768 + c * 1024);
        }
        gld16((const char*)bits + (size_t)(gnext + lane) * (G_ / 8) + (htile >> 3),
              smem + OFF_BITS + sln * 1024);
        // [b] S(it+1) double-buffered
        stage_S(Ff_b, Aj, smem, w, lane, gnext, sln);

        // [B1] S(it) in LDS; does NOT retire this iter's prefetches or any store
        WAITV(21); SBAR; SCHED0;

        // ---- attn^T: acc[h][g] = ai[:,h]·f[g] + f[h]·aj[:,g] ----
        f32x4 acc[2][2];
        #pragma unroll
        for (int i = 0; i < 2; ++i)
            #pragma unroll
            for (int j = 0; j < 2; ++j) acc[i][j] = zz;
        {
            const char* bfg = smem + OFF_FG + sl * 16384;
            const char* baj = smem + OFF_AJ + sl * 16384;
            #pragma unroll
            for (int ks = 0; ks < 4; ++ks) {
                v8bf fgv[2], ajv[2];
                #pragma unroll
                for (int nf = 0; nf < 2; ++nf) {
                    int c = (2 * wg + nf) * 4 + ks;
                    fgv[nf] = *(const v8bf*)(bfg + c * 1024 + lane * 16);
                    ajv[nf] = *(const v8bf*)(baj + c * 1024 + lane * 16);
                }
                #pragma unroll
                for (int mf = 0; mf < 2; ++mf)
                    #pragma unroll
                    for (int nf = 0; nf < 2; ++nf) {
                        acc[mf][nf] = __builtin_amdgcn_mfma_f32_16x16x32_bf16(aih[mf][ks], fgv[nf], acc[mf][nf], 0, 0, 0);
                        acc[mf][nf] = __builtin_amdgcn_mfma_f32_16x16x32_bf16(fh[mf][ks],  ajv[nf], acc[mf][nf], 0, 0, 0);
                    }
            }
        }

        // [B2] bias(it)+bits(it) in LDS (staged one iter ago); stores NOT forced
        WAITV(25); SBAR; SCHED0;

        // ---- epilogue: bias + mask + sigmoid -> gate (f32, dwordx4) + gate^T (LDS bf16) ----
        #pragma unroll
        for (int nf = 0; nf < 2; ++nf) {
            int gl = 32 * wg + 16 * nf + l15;
            unsigned word = *(const unsigned*)(smem + OFF_BITS + sl * 1024 + gl * 16 + wh * 4);
            #pragma unroll
            for (int mf = 0; mf < 2; ++mf) {
                int h0 = 32 * wh + 16 * mf + 4 * l4;
                f32x4 bav = *(const f32x4*)(smem + OFF_BA + sl * 32768 + gl * 512 + ((h0 * 4) ^ ((gl & 7) << 4)));
                f32x4 gs;
                #pragma unroll
                for (int r = 0; r < 4; ++r) {
                    float attnv = acc[mf][nf][r] + bav[r];
                    float e = __expf(-attnv);
                    float gv = __builtin_amdgcn_rcpf(1.0f + e);
                    unsigned bit = (word >> (16 * mf + 4 * l4 + r)) & 1u;
                    gv = bit ? gv : 0.0f;
                    gs[r] = gv;
                    int hL = h0 + r;
                    *(unsigned short*)(smem + OFF_GT + hL * 128 + ((gl * 2) ^ ((hL & 7) << 4))) = f2bf(gv);
                }
                *(f32x4*)(gate_b + (size_t)(gtile + gl) * G_ + htile + h0) = gs;
            }
        }

        // [B3] gate^T visible; lgkm only — stores keep sailing
        LGKM0; SBAR; SCHED0;

        // ---- agg[h][u] += gate^T @ fT ----
        #pragma unroll
        for (int ks = 0; ks < 2; ++ks) {
            v8bf ag[2];
            #pragma unroll
            for (int amf = 0; amf < 2; ++amf) {
                int hL = 16 * (2 * wh + amf) + l15;
                ag[amf] = *(const v8bf*)(smem + OFF_GT + hL * 128 + (((32 * ks + 8 * l4) * 2) ^ ((hL & 7) << 4)));
            }
            #pragma unroll
            for (int amf = 0; amf < 2; ++amf)
                #pragma unroll
                for (int nf = 0; nf < 4; ++nf)
                    agga[amf][nf] = __builtin_amdgcn_mfma_f32_16x16x32_bf16(ag[amf], bfv[nf][ks], agga[amf][nf], 0, 0, 0);
        }
    }

    // write agg partial
    #pragma unroll
    for (int amf = 0; amf < 2; ++amf)
        #pragma unroll
        for (int nf = 0; nf < 4; ++nf) {
            int u = 64 * au + 16 * nf + l15;
            #pragma unroll
            for (int r = 0; r < 4; ++r) {
                int h = htile + 32 * wh + 16 * amf + 4 * l4 + r;
                part[(((size_t)b * 2 + split) << 19) + (size_t)h * U_ + u] = agga[amf][nf][r];
            }
        }
}

// ---------------- reduce: out = relu(part0 + part1 + g2) (g2 already in d_out) ----------
__global__ __launch_bounds__(256) void k_reduce(const float4* __restrict__ part, float4* __restrict__ outio)
{
    int i = blockIdx.x * 256 + threadIdx.x;     // 0..524287 float4s
    int fb = i >> 17, r = i & 0x1FFFF;
    const float4* p = part + ((size_t)fb << 18) + r;
    float4 p0 = p[0];
    float4 p1 = p[(size_t)1 << 17];
    float4 g = outio[i];
    float4 o;
    o.x = fmaxf(p0.x + p1.x + g.x, 0.f);
    o.y = fmaxf(p0.y + p1.y + g.y, 0.f);
    o.z = fmaxf(p0.z + p1.z + g.z, 0.f);
    o.w = fmaxf(p0.w + p1.w + g.w, 0.f);
    outio[i] = o;
}

extern "C" void kernel_launch(void* const* d_in, const int* in_sizes, int n_in,
                              void* d_out, int out_size, void* d_ws, size_t ws_size,
                              hipStream_t stream)
{
    (void)in_sizes; (void)n_in; (void)out_size; (void)ws_size;
    const float* x   = (const float*)d_in[0];
    const float* adj = (const float*)d_in[1];
    const float* w   = (const float*)d_in[2];
    const float* ai  = (const float*)d_in[3];
    const float* aj  = (const float*)d_in[4];
    const float* w2  = (const float*)d_in[5];
    const float* ba  = (const float*)d_in[6];

    char* ws = (char*)d_ws;
    unsigned short* Ff  = (unsigned short*)(ws);                        // 4 MiB
    unsigned short* FfT = (unsigned short*)(ws + ((size_t)4 << 20));    // 4 MiB
    unsigned short* Ai  = (unsigned short*)(ws + ((size_t)8 << 20));    // 1 MiB
    unsigned short* Aj  = (unsigned short*)(ws + ((size_t)9 << 20));    // 1 MiB
    unsigned short* wT  = (unsigned short*)(ws + ((size_t)10 << 20));   // 64 KiB
    unsigned short* w2T = (unsigned short*)(ws + ((size_t)10 << 20) + (1 << 17));
    unsigned* bitsb     = (unsigned*)(ws + ((size_t)11 << 20));         // 2 MiB
    float* part         = (float*)(ws + ((size_t)13 << 20));            // 16 MiB [B][2][G][U]

    float* out  = (float*)d_out;                       // [B*G*U]
    float* gate = out + (size_t)B_ * G_ * U_;          // [B*G*G]

    k_transpose_w   <<<dim3(16),   dim3(256), 0, stream>>>(w, w2, wT, w2T);
    k_transpose_aiaj<<<dim3(128),  dim3(256), 0, stream>>>(ai, aj, Ai, Aj);
    k_pack          <<<dim3(1024), dim3(256), 0, stream>>>(adj, bitsb);
    k_gemm_f        <<<dim3(128),  dim3(256), 0, stream>>>(x, wT, w2T, Ff, FfT, out);
    k_main          <<<dim3(256),  dim3(512), 0, stream>>>(Ff, FfT, Ai, Aj, ba, bitsb, gate, part);
    k_reduce        <<<dim3(2048), dim3(256), 0, stream>>>((const float4*)part, (float4*)out);
}

// Round 6
// 216.827 us; speedup vs baseline: 1.4212x; 1.0408x over previous
//
#include <hip/hip_runtime.h>
#include <hip/hip_bf16.h>

#define B_ 4
#define G_ 4096
#define F_ 256
#define U_ 128

typedef __bf16 v8bf __attribute__((ext_vector_type(8)));
typedef float f32x4 __attribute__((ext_vector_type(4)));

__device__ __forceinline__ unsigned short f2bf(float x) {
    union { float f; unsigned u; } v; v.f = x;
    unsigned r = v.u + 0x7FFFu + ((v.u >> 16) & 1u);
    return (unsigned short)(r >> 16);
}

typedef const __attribute__((address_space(1))) unsigned int* gas_t;
typedef __attribute__((address_space(3))) unsigned int* las_t;

// async global->LDS, 16B/lane; LDS dest = uniform base + lane*16; global src per-lane
__device__ __forceinline__ void gld16(const void* g, const void* l) {
    __builtin_amdgcn_global_load_lds((gas_t)(unsigned long long)g,
                                     (las_t)(unsigned)(unsigned long long)l, 16, 0, 0);
}

#define WAITV(n) asm volatile("s_waitcnt vmcnt(" #n ")" ::: "memory")
#define LGKM0    asm volatile("s_waitcnt lgkmcnt(0)" ::: "memory")
#define SBAR     __builtin_amdgcn_s_barrier()
#define SCHED0   __builtin_amdgcn_sched_barrier(0)

// Fragment-major convention: [row16-blk][k32-blk][lane][8 bf16];
// lane = ((k>>3)&3)*16 + (row&15). One frag load = 1KB coalesced / contiguous LDS.

// LDS arena (56 KB -> 2 blocks/CU; that is the whole point of this round)
#define OFF_FG   0        // 2 x 8KB dbuf: Ff[g32-tile] frags
#define OFF_AJ   16384    // 2 x 8KB dbuf: Aj[g32-tile] frags
#define OFF_BA   32768    // 2 x 8KB dbuf: fused bias bf16 [g32][h128], 16B-XOR-swizzled rows
#define OFF_GT   49152    // 8KB: gate^T bf16 [h128][g32], 16B-XOR-swizzled rows
#define LDS_SZ   57344

// ---------------- prep: transpose w,w2 [256][128]f32 -> wT [128][256]bf16 ----------------
__global__ __launch_bounds__(256) void k_transpose_w(
    const float* __restrict__ w, const float* __restrict__ w2,
    unsigned short* __restrict__ wT, unsigned short* __restrict__ w2T)
{
    int bx = blockIdx.x;
    const float* src = (bx & 1) ? w2 : w;
    unsigned short* dst = (bx & 1) ? w2T : wT;
    int u = threadIdx.x & 127;
    int kseg = (threadIdx.x >> 7) + (bx >> 1) * 2;   // 0..15
    #pragma unroll
    for (int k = 0; k < 16; ++k) {
        int kk = kseg * 16 + k;
        dst[(size_t)u * F_ + kk] = f2bf(src[(size_t)kk * U_ + u]);
    }
}

// ---------------- prep: ai,aj [128][4096]f32 -> Ai/Aj fragment-major bf16 (1 MiB each) ---
__global__ __launch_bounds__(256) void k_transpose_aiaj(
    const float* __restrict__ ai, const float* __restrict__ aj,
    unsigned short* __restrict__ Ai, unsigned short* __restrict__ Aj)
{
    __shared__ unsigned short s_t[64 * 128];
    int blk = blockIdx.x;
    const float* src = (blk < 64) ? ai : aj;
    unsigned short* dst = (blk < 64) ? Ai : Aj;
    int gtile = (blk & 63) * 64;
    int tid = threadIdx.x;
    int gl = tid & 63, ub = tid >> 6;
    #pragma unroll
    for (int i = 0; i < 32; ++i) {
        int u = ub * 32 + i;
        float v = src[(size_t)u * G_ + gtile + gl];
        int ad = ((gl << 8) + (u << 1)) ^ ((gl & 7) << 4);
        *(unsigned short*)((char*)s_t + ad) = f2bf(v);
    }
    __syncthreads();
    // emit fragment-major: 16 chunks (r4 0..3 x k5 0..3), 16 threads/chunk, 4 lanes each
    int c = tid >> 4, sub = tid & 15;
    int g4l = c >> 2, k5 = c & 3;
    #pragma unroll
    for (int q = 0; q < 4; ++q) {
        int l = sub * 4 + q;
        int g = g4l * 16 + (l & 15);
        int u = k5 * 32 + (l >> 4) * 8;
        uint4 v = *(const uint4*)((const char*)s_t + (g << 8) + ((u << 1) ^ ((g & 7) << 4)));
        *(uint4*)(dst + (((size_t)((gtile >> 4) + g4l) * 4 + k5) * 64 + l) * 8) = v;
    }
}

// ---------------- prep: fused bias bf16: ct16[g][h] = bf16(b_a + 1e9*adj - 1e9) ----------
__global__ __launch_bounds__(256) void k_bias16(
    const float* __restrict__ adj, const float* __restrict__ ba,
    unsigned short* __restrict__ ct)
{
    size_t i = ((size_t)blockIdx.x * 256 + threadIdx.x) * 8;
    float4 a0 = *(const float4*)(adj + i);
    float4 a1 = *(const float4*)(adj + i + 4);
    float4 b0 = *(const float4*)(ba + i);
    float4 b1 = *(const float4*)(ba + i + 4);
    union { unsigned short s[8]; uint4 v; } o;
    o.s[0] = f2bf(fmaf(a0.x, 1e9f, -1e9f) + b0.x);
    o.s[1] = f2bf(fmaf(a0.y, 1e9f, -1e9f) + b0.y);
    o.s[2] = f2bf(fmaf(a0.z, 1e9f, -1e9f) + b0.z);
    o.s[3] = f2bf(fmaf(a0.w, 1e9f, -1e9f) + b0.w);
    o.s[4] = f2bf(fmaf(a1.x, 1e9f, -1e9f) + b1.x);
    o.s[5] = f2bf(fmaf(a1.y, 1e9f, -1e9f) + b1.y);
    o.s[6] = f2bf(fmaf(a1.z, 1e9f, -1e9f) + b1.z);
    o.s[7] = f2bf(fmaf(a1.w, 1e9f, -1e9f) + b1.w);
    *(uint4*)(ct + i) = o.v;
}

// ---------------- f = bf16(x@w) -> Ff/FfT fragment-major, g2 = f32(x@w_2) -> d_out -------
__global__ __launch_bounds__(256, 2) void k_gemm_f(
    const float* __restrict__ x,
    const unsigned short* __restrict__ wT, const unsigned short* __restrict__ w2T,
    unsigned short* __restrict__ Ff, unsigned short* __restrict__ FfT,
    float* __restrict__ g2_out)
{
    __shared__ unsigned short s_xa[128 * 128];
    __shared__ unsigned short s_w[128 * 128];
    __shared__ unsigned short s_w2[128 * 128];
    const int tid = threadIdx.x;
    const int lane = tid & 63, w = tid >> 6;
    const int l15 = lane & 15, l4 = lane >> 4;
    const int wm = w >> 1, wn = w & 1;
    const int mrow0 = blockIdx.x * 128;

    f32x4 zz = {0.f, 0.f, 0.f, 0.f};
    f32x4 accf[4][4], accg[4][4];
    #pragma unroll
    for (int i = 0; i < 4; ++i)
        #pragma unroll
        for (int j = 0; j < 4; ++j) { accf[i][j] = zz; accg[i][j] = zz; }

    for (int kc = 0; kc < 2; ++kc) {
        if (kc) __syncthreads();
        {   // stage x tile (f32 -> bf16, swizzled)
            int m = tid >> 1, half = tid & 1;
            const float* src = x + (size_t)(mrow0 + m) * F_ + kc * 128 + half * 64;
            unsigned tmp32[32];
            #pragma unroll
            for (int i = 0; i < 16; ++i) {
                float4 v = *(const float4*)(src + i * 4);
                tmp32[i * 2 + 0] = (unsigned)f2bf(v.x) | ((unsigned)f2bf(v.y) << 16);
                tmp32[i * 2 + 1] = (unsigned)f2bf(v.z) | ((unsigned)f2bf(v.w) << 16);
            }
            #pragma unroll
            for (int gi2 = 0; gi2 < 8; ++gi2) {
                int ad = (m << 8) + ((half * 128 + gi2 * 16) ^ ((m & 7) << 4));
                *(uint4*)((char*)s_xa + ad) = *(const uint4*)(tmp32 + gi2 * 4);
            }
        }
        #pragma unroll
        for (int i = 0; i < 8; ++i) {     // stage wT / w2T chunks
            int c = w * 8 + i;
            int row = c * 4 + l4;
            int Wp = (l15 << 4) ^ ((row & 7) << 4);
            gld16((const char*)wT  + (size_t)row * 512 + kc * 256 + Wp, (const char*)s_w  + c * 1024);
            gld16((const char*)w2T + (size_t)row * 512 + kc * 256 + Wp, (const char*)s_w2 + c * 1024);
        }
        __syncthreads();
        #pragma unroll
        for (int ks = 0; ks < 4; ++ks) {
            int kb = 64 * ks + 16 * l4;
            v8bf a[4], b1[4], b2[4];
            #pragma unroll
            for (int mf = 0; mf < 4; ++mf) {
                int m = l15 + 16 * mf + 64 * wm;
                int ad = (m << 8) + (kb ^ ((m & 7) << 4));
                a[mf] = *(const v8bf*)((const char*)s_xa + ad);
            }
            #pragma unroll
            for (int nf = 0; nf < 4; ++nf) {
                int u = l15 + 16 * nf + 64 * wn;
                int ad = (u << 8) + (kb ^ ((u & 7) << 4));
                b1[nf] = *(const v8bf*)((const char*)s_w + ad);
                b2[nf] = *(const v8bf*)((const char*)s_w2 + ad);
            }
            #pragma unroll
            for (int mf = 0; mf < 4; ++mf)
                #pragma unroll
                for (int nf = 0; nf < 4; ++nf) {
                    accf[mf][nf] = __builtin_amdgcn_mfma_f32_16x16x32_bf16(a[mf], b1[nf], accf[mf][nf], 0, 0, 0);
                    accg[mf][nf] = __builtin_amdgcn_mfma_f32_16x16x32_bf16(a[mf], b2[nf], accg[mf][nf], 0, 0, 0);
                }
        }
    }
    const int b = mrow0 >> 12, gb = mrow0 & 4095;
    // g2 (f32) direct to d_out
    #pragma unroll
    for (int mf = 0; mf < 4; ++mf)
        #pragma unroll
        for (int nf = 0; nf < 4; ++nf)
            #pragma unroll
            for (int r = 0; r < 4; ++r) {
                int m = 4 * l4 + r + 16 * mf + 64 * wm;
                int u = l15 + 16 * nf + 64 * wn;
                g2_out[(size_t)(mrow0 + m) * U_ + u] = accg[mf][nf][r];
            }
    // bounce f tile (bf16) into s_xa
    __syncthreads();
    #pragma unroll
    for (int mf = 0; mf < 4; ++mf)
        #pragma unroll
        for (int nf = 0; nf < 4; ++nf)
            #pragma unroll
            for (int r = 0; r < 4; ++r) {
                int m = 4 * l4 + r + 16 * mf + 64 * wm;
                int u = l15 + 16 * nf + 64 * wn;
                int ad = (m << 8) + ((u << 1) ^ ((m & 7) << 4));
                *(unsigned short*)((char*)s_xa + ad) = f2bf(accf[mf][nf][r]);
            }
    __syncthreads();
    // emit Ff: 32 chunks (g4l 0..7 x k5 0..3)
    {
        unsigned short* Ffb = Ff + (size_t)b * (G_ * U_);
        int c = tid >> 3, sub = tid & 7;
        int g4l = c >> 2, k5 = c & 3;
        #pragma unroll
        for (int q = 0; q < 8; ++q) {
            int l = sub * 8 + q;
            int m = g4l * 16 + (l & 15);
            int k = k5 * 32 + (l >> 4) * 8;
            uint4 v = *(const uint4*)((const char*)s_xa + (m << 8) + ((k << 1) ^ ((m & 7) << 4)));
            *(uint4*)(Ffb + (((size_t)((gb >> 4) + g4l) * 4 + k5) * 64 + l) * 8) = v;
        }
    }
    // emit FfT: 32 chunks (u4 0..7 x g5l 0..3), gather-transpose from s_xa
    {
        unsigned short* FfTb = FfT + (size_t)b * (G_ * U_);
        int c = tid >> 3, sub = tid & 7;
        int u4 = c >> 2, g5l = c & 3;
        #pragma unroll
        for (int q = 0; q < 8; ++q) {
            int l = sub * 8 + q;
            int u = u4 * 16 + (l & 15);
            int g0l = g5l * 32 + (l >> 4) * 8;
            union { unsigned short s[8]; uint4 v; } pk;
            #pragma unroll
            for (int j = 0; j < 8; ++j) {
                int m = g0l + j;
                pk.s[j] = *(const unsigned short*)((const char*)s_xa + (m << 8) + ((u << 1) ^ ((m & 7) << 4)));
            }
            *(uint4*)(FfTb + (((size_t)u4 * 128 + (gb >> 5) + g5l) * 64 + l) * 8) = pk.v;
        }
    }
}

// ---------------- k_main helpers ----------------
__device__ __forceinline__ void stage_S(const unsigned short* Ff_b, const unsigned short* Aj,
                                        char* smem, int w, int lane, int gt, int slot)
{
    // FG/AJ tile: 8 chunks of 1KB (g4l = c>>2 in 0..1, ks = c&3); chunk c = w
    size_t off = ((((size_t)(gt >> 4) + (w >> 2)) * 4 + (w & 3)) * 64 + lane) * 16;
    gld16((const char*)Ff_b + off, smem + OFF_FG + slot * 8192 + w * 1024);
    gld16((const char*)Aj  + off, smem + OFF_AJ + slot * 8192 + w * 1024);
}

__device__ __forceinline__ void stage_BA(const unsigned short* ct, char* smem,
                                         int w, int lane, int gt, int htile, int slot)
{
    // bias tile [g32][h128] bf16 = 8KB; row = 256B; chunk w = rows 4w..4w+3
    int row = 4 * w + (lane >> 4);
    int src = ((lane & 15) * 16) ^ ((row & 7) << 4);   // pre-swizzled source, linear LDS dest
    gld16((const char*)ct + ((size_t)(gt + row) * G_ + htile) * 2 + src,
          smem + OFF_BA + slot * 8192 + w * 1024);
}

// Per-iter VMEM issue order (per thread), FIFO-counted:
//   [c] bfv 8   [a] bias(it+1) 1   [b] S(it+1) 2   B1  attn  B2  [e] gate-stores 2  B3  agg
// B1 needs [b](it) (top of it-1): newer = e(it-1)2 + c8 + a1 + b2            = 13
// B2 needs [a](it) (top of it-1): newer = b(it)2 + e(it-1)2 + c8 + a1 + b2   = 15
// B3 needs [c](it):               newer = a1 + b2 + e(it)2                   = 5
// No wait ever forces a store to retire (stores are always among the "newer" set).
__global__ __launch_bounds__(512, 4) void k_main(
    const unsigned short* __restrict__ Ff,   // [B] frag-major f
    const unsigned short* __restrict__ FfT,  // [B] frag-major fT [u4][g5][lane][8]
    const unsigned short* __restrict__ Ai,   // frag-major aiT
    const unsigned short* __restrict__ Aj,   // frag-major ajT
    const unsigned short* __restrict__ ct16, // [G][G] bf16 fused bias (b_a - 1e9*(1-adj))
    float* __restrict__ gate_out,            // [B][G][G] f32
    float* __restrict__ part)                // [B][4][G][U] f32
{
    __shared__ __align__(1024) char smem[LDS_SZ];
    const int tid = threadIdx.x;
    const int lane = tid & 63, w = tid >> 6;     // w = h16-block owned by this wave
    const int l15 = lane & 15, l4 = lane >> 4;
    // XCD-clustering: the 4 batches of one (split,htile) tile land on one XCD under both
    // round-robin (bid&7) and 32-chunked blockIdx->XCD mappings -> bias/Ff fetched once per XCD.
    const int bid = blockIdx.x;
    const int xcd = bid & 7;
    const int rest = bid >> 3;                   // 0..63
    const int b = rest & 3;
    const int tile = (rest >> 2) * 8 + xcd;      // 0..127
    const int split = tile & 3;
    const int htile = (tile >> 2) * 128;

    const unsigned short* Ff_b  = Ff  + (size_t)b * (G_ * U_);
    const unsigned short* FfT_b = FfT + (size_t)b * (G_ * U_);
    float* gate_b = gate_out + ((size_t)b << 24);

    // ---- prologue: Ai[htile] then Ff[htile] through LDS into per-wave registers ----
    #pragma unroll
    for (int i = 0; i < 4; ++i) {
        int c = 4 * w + i;
        size_t off = ((((size_t)(htile >> 4) + (c >> 2)) * 4 + (c & 3)) * 64 + lane) * 16;
        gld16((const char*)Ai + off, smem + c * 1024);
    }
    WAITV(0); SBAR;
    v8bf aih[4], fh[4];
    #pragma unroll
    for (int ks = 0; ks < 4; ++ks)
        aih[ks] = *(const v8bf*)(smem + (4 * w + ks) * 1024 + lane * 16);
    LGKM0; SBAR;
    #pragma unroll
    for (int i = 0; i < 4; ++i) {
        int c = 4 * w + i;
        size_t off = ((((size_t)(htile >> 4) + (c >> 2)) * 4 + (c & 3)) * 64 + lane) * 16;
        gld16((const char*)Ff_b + off, smem + c * 1024);
    }
    WAITV(0); SBAR;
    #pragma unroll
    for (int ks = 0; ks < 4; ++ks)
        fh[ks] = *(const v8bf*)(smem + (4 * w + ks) * 1024 + lane * 16);
    LGKM0; SBAR;
    // prime iter 0
    stage_BA(ct16, smem, w, lane, split * 1024, htile, 0);
    stage_S(Ff_b, Aj, smem, w, lane, split * 1024, 0);
    WAITV(0); SBAR;

    f32x4 zz = {0.f, 0.f, 0.f, 0.f};
    f32x4 agga[8];
    #pragma unroll
    for (int i = 0; i < 8; ++i) agga[i] = zz;

    for (int it = 0; it < 32; ++it) {
        const int gtile = split * 1024 + it * 32;
        const int itn = (it < 31) ? it + 1 : 31;          // clamp: same op count, no OOB
        const int gnext = split * 1024 + itn * 32;
        const int sl = it & 1, sln = (it + 1) & 1;

        // [c] bfv: FfT B-frags for agg, direct from global (L2-resident on this XCD)
        v8bf bfv[8];
        #pragma unroll
        for (int u4 = 0; u4 < 8; ++u4)
            bfv[u4] = *(const v8bf*)((const char*)FfT_b +
                (((size_t)u4 * 128 + (gtile >> 5)) * 64 + lane) * 16);
        // [a] bias(it+1), [b] S(it+1): one full iteration of latency cover
        stage_BA(ct16, smem, w, lane, gnext, htile, sln);
        stage_S(Ff_b, Aj, smem, w, lane, gnext, sln);

        // [B1] S(it) in LDS; stores not forced
        WAITV(13); SBAR; SCHED0;

        // ---- attn^T: acc[h][g] = ai[:,h]·f[g] + f[h]·aj[:,g]  (16h x 32g per wave) ----
        f32x4 acc[2] = {zz, zz};
        {
            const char* bfg = smem + OFF_FG + sl * 8192;
            const char* baj = smem + OFF_AJ + sl * 8192;
            #pragma unroll
            for (int ks = 0; ks < 4; ++ks) {
                #pragma unroll
                for (int nf = 0; nf < 2; ++nf) {
                    v8bf fgv = *(const v8bf*)(bfg + (nf * 4 + ks) * 1024 + lane * 16);
                    v8bf ajv = *(const v8bf*)(baj + (nf * 4 + ks) * 1024 + lane * 16);
                    acc[nf] = __builtin_amdgcn_mfma_f32_16x16x32_bf16(aih[ks], fgv, acc[nf], 0, 0, 0);
                    acc[nf] = __builtin_amdgcn_mfma_f32_16x16x32_bf16(fh[ks],  ajv, acc[nf], 0, 0, 0);
                }
            }
        }

        // [B2] bias(it) in LDS (staged one iter ago); stores not forced
        WAITV(15); SBAR; SCHED0;

        // ---- epilogue: fused bias + sigmoid -> gate (f32 dwordx4) + gate^T (LDS bf16) ----
        #pragma unroll
        for (int nf = 0; nf < 2; ++nf) {
            int g = 16 * nf + l15;               // tile-local g row
            int h0 = 16 * w + 4 * l4;            // htile-local h
            ushort4 bu = *(const ushort4*)(smem + OFF_BA + sl * 8192 + g * 256 +
                                           ((h0 * 2) ^ ((g & 7) << 4)));
            f32x4 gs;
            #pragma unroll
            for (int r = 0; r < 4; ++r) {
                union { unsigned u; float f; } cv;
                cv.u = ((unsigned)(&bu.x)[r]) << 16;
                float attnv = acc[nf][r] + cv.f;             // non-edge: ~-1e9 -> gate 0 exactly
                float e = __expf(-attnv);
                float gv = __builtin_amdgcn_rcpf(1.0f + e);
                gs[r] = gv;
                int hL = h0 + r;
                *(unsigned short*)(smem + OFF_GT + hL * 64 +
                                   ((g * 2) ^ (((hL >> 2) & 3) << 4))) = f2bf(gv);
            }
            *(f32x4*)(gate_b + (size_t)(gtile + g) * G_ + htile + h0) = gs;   // [e]
        }

        // [B3] bfv landed + gate^T visible; stores keep sailing
        WAITV(5); LGKM0; SBAR; SCHED0;

        // ---- agg[h][u] += gate^T @ fT  (K = g32, one MFMA per u-block) ----
        {
            int hr = 16 * w + l15;
            v8bf ag = *(const v8bf*)(smem + OFF_GT + hr * 64 +
                                     ((l4 * 16) ^ (((hr >> 2) & 3) << 4)));
            #pragma unroll
            for (int u4 = 0; u4 < 8; ++u4)
                agga[u4] = __builtin_amdgcn_mfma_f32_16x16x32_bf16(ag, bfv[u4], agga[u4], 0, 0, 0);
        }
    }

    // write agg partial
    #pragma unroll
    for (int u4 = 0; u4 < 8; ++u4)
        #pragma unroll
        for (int r = 0; r < 4; ++r) {
            int h = htile + 16 * w + 4 * l4 + r;
            int u = 16 * u4 + l15;
            part[(((size_t)b * 4 + split) << 19) + (size_t)h * U_ + u] = agga[u4][r];
        }
}

// ---------------- reduce: out = relu(part0..3 + g2) (g2 already in d_out) ----------------
__global__ __launch_bounds__(256) void k_reduce(const float4* __restrict__ part, float4* __restrict__ outio)
{
    int i = blockIdx.x * 256 + threadIdx.x;     // 0..524287 float4s
    int fb = i >> 17, r = i & 0x1FFFF;
    const float4* p = part + (((size_t)fb * 4) << 17) + r;
    float4 p0 = p[0];
    float4 p1 = p[(size_t)1 << 17];
    float4 p2 = p[(size_t)2 << 17];
    float4 p3 = p[(size_t)3 << 17];
    float4 g = outio[i];
    float4 o;
    o.x = fmaxf(p0.x + p1.x + p2.x + p3.x + g.x, 0.f);
    o.y = fmaxf(p0.y + p1.y + p2.y + p3.y + g.y, 0.f);
    o.z = fmaxf(p0.z + p1.z + p2.z + p3.z + g.z, 0.f);
    o.w = fmaxf(p0.w + p1.w + p2.w + p3.w + g.w, 0.f);
    outio[i] = o;
}

extern "C" void kernel_launch(void* const* d_in, const int* in_sizes, int n_in,
                              void* d_out, int out_size, void* d_ws, size_t ws_size,
                              hipStream_t stream)
{
    (void)in_sizes; (void)n_in; (void)out_size; (void)ws_size;
    const float* x   = (const float*)d_in[0];
    const float* adj = (const float*)d_in[1];
    const float* w   = (const float*)d_in[2];
    const float* ai  = (const float*)d_in[3];
    const float* aj  = (const float*)d_in[4];
    const float* w2  = (const float*)d_in[5];
    const float* ba  = (const float*)d_in[6];

    char* ws = (char*)d_ws;
    unsigned short* Ff  = (unsigned short*)(ws);                        // 4 MiB
    unsigned short* FfT = (unsigned short*)(ws + ((size_t)4 << 20));    // 4 MiB
    unsigned short* Ai  = (unsigned short*)(ws + ((size_t)8 << 20));    // 1 MiB
    unsigned short* Aj  = (unsigned short*)(ws + ((size_t)9 << 20));    // 1 MiB
    unsigned short* wT  = (unsigned short*)(ws + ((size_t)10 << 20));   // 64 KiB
    unsigned short* w2T = (unsigned short*)(ws + ((size_t)10 << 20) + (1 << 17));
    float* part         = (float*)(ws + ((size_t)12 << 20));            // 32 MiB [B][4][G][U]
    unsigned short* ct16= (unsigned short*)(ws + ((size_t)44 << 20));   // 32 MiB bf16 fused bias

    float* out  = (float*)d_out;                       // [B*G*U]
    float* gate = out + (size_t)B_ * G_ * U_;          // [B*G*G]

    k_transpose_w   <<<dim3(16),   dim3(256), 0, stream>>>(w, w2, wT, w2T);
    k_transpose_aiaj<<<dim3(128),  dim3(256), 0, stream>>>(ai, aj, Ai, Aj);
    k_bias16        <<<dim3(8192), dim3(256), 0, stream>>>(adj, ba, ct16);
    k_gemm_f        <<<dim3(128),  dim3(256), 0, stream>>>(x, wT, w2T, Ff, FfT, out);
    k_main          <<<dim3(512),  dim3(512), 0, stream>>>(Ff, FfT, Ai, Aj, ct16, gate, part);
    k_reduce        <<<dim3(2048), dim3(256), 0, stream>>>((const float4*)part, (float4*)out);
}